// Round 5
// baseline (922.499 us; speedup 1.0000x reference)
//
#include <hip/hip_runtime.h>
#include <math.h>

#define BB 4
#define NN 1024
#define EE 768
#define HH 12
#define DD 64
#define MLPH 1536
#define RR (BB*NN)
#define SZH ((size_t)48*1024*64)   // elements per split attention array

constexpr float EPS = 1e-6f;

typedef __bf16 bf16_t;
typedef bf16_t bf16x8 __attribute__((ext_vector_type(8)));
typedef bf16_t bf16x4 __attribute__((ext_vector_type(4)));
typedef float  f32x4  __attribute__((ext_vector_type(4)));
typedef unsigned short us8 __attribute__((ext_vector_type(8)));

__device__ __forceinline__ float gelu_exact(float x){
  return 0.5f * x * (1.0f + erff(x * 0.70710678118654752440f));
}

__device__ __forceinline__ bf16x8 negv(bf16x8 v){
  us8 u = __builtin_bit_cast(us8, v);
  u ^= (unsigned short)0x8000;
  return __builtin_bit_cast(bf16x8, u);
}

// split fp32x4 -> hi/lo bf16x4, store to LDS
__device__ __forceinline__ void cvtstore(bf16_t* hp, bf16_t* lp, f32x4 v){
  bf16x4 h, l;
  #pragma unroll
  for (int i=0;i<4;i++){
    float f = v[i];
    bf16_t hb = (bf16_t)f;
    h[i] = hb;
    l[i] = (bf16_t)(f - (float)hb);
  }
  *(bf16x4*)hp = h;
  *(bf16x4*)lp = l;
}

// ---------------- complex layernorm (unchanged) ----------------
__global__ __launch_bounds__(256) void cln_kernel(
    const float* __restrict__ inI,
    const float* __restrict__ inR, const float* __restrict__ inIm,
    const float* __restrict__ gamma, const float* __restrict__ beta,
    float* __restrict__ outR, float* __restrict__ outI, int mode)
{
  int row = blockIdx.x;
  int t = threadIdx.x;
  __shared__ float sbuf[4];
  float vr[3], vi[3], mg[3];
  #pragma unroll
  for (int j=0;j<3;j++){
    int e = t + 256*j;
    float a, b;
    if (mode == 0){
      a = inI[(size_t)row*(2*EE) + 2*e];
      b = inI[(size_t)row*(2*EE) + 2*e + 1];
    } else {
      a = inR[(size_t)row*EE + e];
      b = inIm[(size_t)row*EE + e];
    }
    vr[j]=a; vi[j]=b;
    mg[j] = sqrtf(a*a + b*b + EPS);
  }
  int lane = t & 63, wv = t >> 6;
  float s = mg[0]+mg[1]+mg[2];
  #pragma unroll
  for (int o=32;o>0;o>>=1) s += __shfl_down(s, o, 64);
  if (lane==0) sbuf[wv] = s;
  __syncthreads();
  float mean = (sbuf[0]+sbuf[1]+sbuf[2]+sbuf[3]) * (1.0f/EE);
  __syncthreads();
  float v = 0.f;
  #pragma unroll
  for (int j=0;j<3;j++){ float d = mg[j]-mean; v += d*d; }
  #pragma unroll
  for (int o=32;o>0;o>>=1) v += __shfl_down(v, o, 64);
  if (lane==0) sbuf[wv] = v;
  __syncthreads();
  float var = (sbuf[0]+sbuf[1]+sbuf[2]+sbuf[3]) * (1.0f/EE);
  float inv = 1.0f / sqrtf(var + EPS);
  #pragma unroll
  for (int j=0;j<3;j++){
    int e = t + 256*j;
    float scale = ((mg[j]-mean) * inv) / (mg[j] + EPS);
    outR[(size_t)row*EE + e] = gamma[2*e]   * (vr[j]*scale) + beta[2*e];
    outI[(size_t)row*EE + e] = gamma[2*e+1] * (vi[j]*scale) + beta[2*e+1];
  }
}

// ---------------- complex GEMM via bf16x3 MFMA ----------------
// Fragment-native LDS layout: plane[((row>>4)*4 + koctet)*128 + (row&15)*8 + e]
// -> wave frag reads are 1024B contiguous (bank-floor), staging writes uniform.
// OUT_MODE: 0 planar fp32, 1 interleaved fp32, 2 QKV split bf16 arrays
template<int ACT, int RES_MODE, int OUT_MODE>
__global__ __launch_bounds__(256) void cgemm_mfma(
    const float* __restrict__ xr, const float* __restrict__ xi,
    const float* __restrict__ wr, const float* __restrict__ wi,
    const float* __restrict__ br_, const float* __restrict__ bi_,
    const float* __restrict__ resr, const float* __restrict__ resi,
    float* __restrict__ outr, float* __restrict__ outi,
    bf16_t* __restrict__ qsplit,
    int K, int OUT)
{
  __shared__ bf16_t Arh[4096], Arl[4096], Aih[4096], Ail[4096];  // 128x32
  __shared__ bf16_t Brh[2048], Brl[2048], Bih[2048], Bil[2048];  // 64x32

  const int tid = threadIdx.x;
  const int rowBase = blockIdx.y * 128, colBase = blockIdx.x * 64;

  // staging coords: 8 threads per row-segment of 32 floats
  const int sr = tid >> 3;          // 0..31
  const int sc = (tid & 7) * 4;     // float col 0,4,...,28
  const int so = sc >> 3;           // k-octet 0..3
  const int se = sc & 7;            // 0 or 4

  // compute coords
  const int wid = tid >> 6, lane = tid & 63;
  const int wr0 = (wid >> 1) * 64, wc0 = (wid & 1) * 32;
  const int fr = lane & 15, fq = lane >> 4;

  f32x4 accR[4][2], accI[4][2];
  #pragma unroll
  for (int mi=0;mi<4;mi++)
    #pragma unroll
    for (int ni=0;ni<2;ni++){ accR[mi][ni] = (f32x4)0.f; accI[mi][ni] = (f32x4)0.f; }

  f32x4 pAr[4], pAi[4], pBr[2], pBi[2];

  auto LOAD = [&](int k0){
    #pragma unroll
    for (int it=0; it<4; it++){
      const size_t ro = (size_t)(rowBase + sr + it*32)*K + k0 + sc;
      pAr[it] = *(const f32x4*)(xr + ro);
      pAi[it] = *(const f32x4*)(xi + ro);
    }
    #pragma unroll
    for (int it=0; it<2; it++){
      const size_t ro = (size_t)(colBase + sr + it*32)*K + k0 + sc;
      pBr[it] = *(const f32x4*)(wr + ro);
      pBi[it] = *(const f32x4*)(wi + ro);
    }
  };

  LOAD(0);

  for (int k0 = 0; k0 < K; k0 += 32){
    __syncthreads();
    #pragma unroll
    for (int it=0; it<4; it++){
      int r = sr + it*32;
      int off = ((r>>4)*4 + so)*128 + (r&15)*8 + se;
      cvtstore(&Arh[off], &Arl[off], pAr[it]);
      cvtstore(&Aih[off], &Ail[off], pAi[it]);
    }
    #pragma unroll
    for (int it=0; it<2; it++){
      int r = sr + it*32;
      int off = ((r>>4)*4 + so)*128 + (r&15)*8 + se;
      cvtstore(&Brh[off], &Brl[off], pBr[it]);
      cvtstore(&Bih[off], &Bil[off], pBi[it]);
    }
    __syncthreads();
    if (k0 + 32 < K) LOAD(k0 + 32);

    bf16x8 brh[2], brl[2], bih[2], bil[2];
    #pragma unroll
    for (int ni=0; ni<2; ni++){
      int off = (((wid&1)*2 + ni)*4 + fq)*128 + fr*8;
      brh[ni] = *(const bf16x8*)&Brh[off];
      brl[ni] = *(const bf16x8*)&Brl[off];
      bih[ni] = *(const bf16x8*)&Bih[off];
      bil[ni] = *(const bf16x8*)&Bil[off];
    }
    #pragma unroll
    for (int mi=0; mi<4; mi++){
      int off = (((wid>>1)*4 + mi)*4 + fq)*128 + fr*8;
      bf16x8 arh = *(const bf16x8*)&Arh[off];
      bf16x8 arl = *(const bf16x8*)&Arl[off];
      bf16x8 aih = *(const bf16x8*)&Aih[off];
      bf16x8 ail = *(const bf16x8*)&Ail[off];
      bf16x8 nih = negv(aih), nil_ = negv(ail);
      #pragma unroll
      for (int ni=0; ni<2; ni++){
        f32x4 cR = accR[mi][ni], cI = accI[mi][ni];
        cR = __builtin_amdgcn_mfma_f32_16x16x32_bf16(arh, brh[ni], cR, 0,0,0);
        cR = __builtin_amdgcn_mfma_f32_16x16x32_bf16(arh, brl[ni], cR, 0,0,0);
        cR = __builtin_amdgcn_mfma_f32_16x16x32_bf16(arl, brh[ni], cR, 0,0,0);
        cR = __builtin_amdgcn_mfma_f32_16x16x32_bf16(nih, bih[ni], cR, 0,0,0);
        cR = __builtin_amdgcn_mfma_f32_16x16x32_bf16(nih, bil[ni], cR, 0,0,0);
        cR = __builtin_amdgcn_mfma_f32_16x16x32_bf16(nil_, bih[ni], cR, 0,0,0);
        cI = __builtin_amdgcn_mfma_f32_16x16x32_bf16(arh, bih[ni], cI, 0,0,0);
        cI = __builtin_amdgcn_mfma_f32_16x16x32_bf16(arh, bil[ni], cI, 0,0,0);
        cI = __builtin_amdgcn_mfma_f32_16x16x32_bf16(arl, bih[ni], cI, 0,0,0);
        cI = __builtin_amdgcn_mfma_f32_16x16x32_bf16(aih, brh[ni], cI, 0,0,0);
        cI = __builtin_amdgcn_mfma_f32_16x16x32_bf16(aih, brl[ni], cI, 0,0,0);
        cI = __builtin_amdgcn_mfma_f32_16x16x32_bf16(ail, brh[ni], cI, 0,0,0);
        accR[mi][ni] = cR; accI[mi][ni] = cI;
      }
    }
  }

  #pragma unroll
  for (int mi=0; mi<4; mi++){
    #pragma unroll
    for (int ni=0; ni<2; ni++){
      #pragma unroll
      for (int j=0; j<4; j++){
        int r = rowBase + wr0 + mi*16 + fq*4 + j;
        int c = colBase + wc0 + ni*16 + fr;
        float oR = accR[mi][ni][j] + br_[c];
        float oI = accI[mi][ni][j] + bi_[c];
        if (ACT == 1){ oR = gelu_exact(oR); oI = gelu_exact(oI); }
        if (RES_MODE == 1){
          oR += resr[(size_t)r*OUT + c];
          oI += resi[(size_t)r*OUT + c];
        } else if (RES_MODE == 2){
          oR += resr[(size_t)r*(2*OUT) + 2*c];
          oI += resr[(size_t)r*(2*OUT) + 2*c + 1];
        }
        if (OUT_MODE == 0){
          outr[(size_t)r*OUT + c] = oR;
          outi[(size_t)r*OUT + c] = oI;
        } else if (OUT_MODE == 1){
          outr[(size_t)r*(2*OUT) + 2*c]     = oR;
          outr[(size_t)r*(2*OUT) + 2*c + 1] = oI;
        } else {
          // QKV split bf16: Q,K -> [bh][n][64]; V -> [bh][64][n]
          int part = c / EE; int win = c - part*EE;
          int hh = win >> 6, dd = win & 63;
          int bq = r >> 10, nq = r & 1023;
          int bhh = bq*HH + hh;
          size_t idx = (part < 2) ? (((size_t)bhh*NN + nq)*DD + dd)
                                  : (((size_t)bhh*DD + dd)*NN + nq);
          bf16_t* bas = qsplit + (size_t)part*4*SZH;
          bf16_t hR = (bf16_t)oR; bf16_t lR2 = (bf16_t)(oR - (float)hR);
          bf16_t hI = (bf16_t)oI; bf16_t lI2 = (bf16_t)(oI - (float)hI);
          bas[idx]         = hR;
          bas[SZH + idx]   = lR2;
          bas[2*SZH + idx] = hI;
          bas[3*SZH + idx] = lI2;
        }
      }
    }
  }
}

// ---------------- complex flash attention via MFMA (unchanged) ----------------
__global__ __launch_bounds__(256) void cattn_mfma(
    const bf16_t* __restrict__ qs,
    float* __restrict__ aor, float* __restrict__ aoi)
{
  __shared__ bf16_t Krh[32][72], Krl[32][72], Kih[32][72], Kil[32][72];
  __shared__ bf16_t Vrh[64][40], Vrl[64][40], Vih[64][40], Vil[64][40];
  __shared__ bf16_t Pl[4][16][40];

  const int tid = threadIdx.x;
  const int lane = tid & 63, wid = tid >> 6;
  const int fr = lane & 15, fq = lane >> 4;
  const int qt = blockIdx.x, bh = blockIdx.y;
  const int b = bh / HH, h = bh - b*HH;

  const bf16_t* Qb = qs;
  const bf16_t* Kb = qs + 4*SZH;
  const bf16_t* Vb = qs + 8*SZH;

  const int qrow = qt*64 + wid*16 + fr;
  bf16x8 q_rh[2], q_rl[2], q_ih[2], q_il[2], nq_ih[2], nq_il[2];
  #pragma unroll
  for (int c=0;c<2;c++){
    size_t o = ((size_t)bh*NN + qrow)*DD + c*32 + fq*8;
    q_rh[c] = *(const bf16x8*)(Qb + 0*SZH + o);
    q_rl[c] = *(const bf16x8*)(Qb + 1*SZH + o);
    q_ih[c] = *(const bf16x8*)(Qb + 2*SZH + o);
    q_il[c] = *(const bf16x8*)(Qb + 3*SZH + o);
    nq_ih[c] = negv(q_ih[c]);
    nq_il[c] = negv(q_il[c]);
  }

  f32x4 accOr[4], accOi[4];
  #pragma unroll
  for (int df=0;df<4;df++){ accOr[df] = (f32x4)0.f; accOi[df] = (f32x4)0.f; }
  float m[4] = {0.f,0.f,0.f,0.f}, l[4] = {0.f,0.f,0.f,0.f};

  const int skr = tid >> 3, skc = (tid & 7) * 8;   // K stage: 32 x 64
  const int svr = tid >> 2, svc = (tid & 3) * 8;   // V stage: 64 x 32

  for (int kt = 0; kt < NN/32; kt++){
    __syncthreads();
    {
      size_t kb = ((size_t)bh*NN + kt*32 + skr)*DD + skc;
      *(bf16x8*)&Krh[skr][skc] = *(const bf16x8*)(Kb + 0*SZH + kb);
      *(bf16x8*)&Krl[skr][skc] = *(const bf16x8*)(Kb + 1*SZH + kb);
      *(bf16x8*)&Kih[skr][skc] = *(const bf16x8*)(Kb + 2*SZH + kb);
      *(bf16x8*)&Kil[skr][skc] = *(const bf16x8*)(Kb + 3*SZH + kb);
      size_t vb = ((size_t)bh*DD + svr)*NN + kt*32 + svc;
      *(bf16x8*)&Vrh[svr][svc] = *(const bf16x8*)(Vb + 0*SZH + vb);
      *(bf16x8*)&Vrl[svr][svc] = *(const bf16x8*)(Vb + 1*SZH + vb);
      *(bf16x8*)&Vih[svr][svc] = *(const bf16x8*)(Vb + 2*SZH + vb);
      *(bf16x8*)&Vil[svr][svc] = *(const bf16x8*)(Vb + 3*SZH + vb);
    }
    __syncthreads();

    f32x4 sr[2], si[2];
    #pragma unroll
    for (int f=0; f<2; f++){
      f32x4 r = (f32x4)0.f, im = (f32x4)0.f;
      #pragma unroll
      for (int c=0; c<2; c++){
        const int kr_ = f*16 + fr, co = c*32 + fq*8;
        bf16x8 krh = *(const bf16x8*)&Krh[kr_][co];
        bf16x8 krl = *(const bf16x8*)&Krl[kr_][co];
        bf16x8 kih = *(const bf16x8*)&Kih[kr_][co];
        bf16x8 kil = *(const bf16x8*)&Kil[kr_][co];
        r = __builtin_amdgcn_mfma_f32_16x16x32_bf16(q_rh[c], krh, r, 0,0,0);
        r = __builtin_amdgcn_mfma_f32_16x16x32_bf16(q_rh[c], krl, r, 0,0,0);
        r = __builtin_amdgcn_mfma_f32_16x16x32_bf16(q_rl[c], krh, r, 0,0,0);
        r = __builtin_amdgcn_mfma_f32_16x16x32_bf16(q_ih[c], kih, r, 0,0,0);
        r = __builtin_amdgcn_mfma_f32_16x16x32_bf16(q_ih[c], kil, r, 0,0,0);
        r = __builtin_amdgcn_mfma_f32_16x16x32_bf16(q_il[c], kih, r, 0,0,0);
        im = __builtin_amdgcn_mfma_f32_16x16x32_bf16(q_rh[c], kih, im, 0,0,0);
        im = __builtin_amdgcn_mfma_f32_16x16x32_bf16(q_rh[c], kil, im, 0,0,0);
        im = __builtin_amdgcn_mfma_f32_16x16x32_bf16(q_rl[c], kih, im, 0,0,0);
        im = __builtin_amdgcn_mfma_f32_16x16x32_bf16(nq_ih[c], krh, im, 0,0,0);
        im = __builtin_amdgcn_mfma_f32_16x16x32_bf16(nq_ih[c], krl, im, 0,0,0);
        im = __builtin_amdgcn_mfma_f32_16x16x32_bf16(nq_il[c], krh, im, 0,0,0);
      }
      sr[f] = r; si[f] = im;
    }

    float mg[2][4];
    #pragma unroll
    for (int f=0; f<2; f++)
      #pragma unroll
      for (int j=0; j<4; j++){
        float a = sr[f][j], c2 = si[f][j];
        mg[f][j] = sqrtf(fmaf(a,a, fmaf(c2,c2, 1e-8f))) * 0.125f;
      }
    float al[4];
    #pragma unroll
    for (int j=0; j<4; j++){
      float mx = fmaxf(mg[0][j], mg[1][j]);
      mx = fmaxf(mx, __shfl_xor(mx, 1, 64));
      mx = fmaxf(mx, __shfl_xor(mx, 2, 64));
      mx = fmaxf(mx, __shfl_xor(mx, 4, 64));
      mx = fmaxf(mx, __shfl_xor(mx, 8, 64));
      float nm = fmaxf(m[j], mx);
      al[j] = __expf(m[j] - nm);
      m[j] = nm;
    }
    unsigned pk[4]; float psum[4];
    #pragma unroll
    for (int j=0; j<4; j++){
      float p0 = __expf(mg[0][j] - m[j]);
      float p1 = __expf(mg[1][j] - m[j]);
      bf16_t b0 = (bf16_t)p0, b1 = (bf16_t)p1;
      pk[j] = (unsigned)__builtin_bit_cast(unsigned short, b0)
            | ((unsigned)__builtin_bit_cast(unsigned short, b1) << 16);
      psum[j] = (float)b0 + (float)b1;
    }
    #pragma unroll
    for (int j=0; j<4; j++){
      float s = psum[j];
      s += __shfl_xor(s, 1, 64);
      s += __shfl_xor(s, 2, 64);
      s += __shfl_xor(s, 4, 64);
      s += __shfl_xor(s, 8, 64);
      l[j] = l[j]*al[j] + s;
      #pragma unroll
      for (int df=0; df<4; df++){ accOr[df][j] *= al[j]; accOi[df][j] *= al[j]; }
    }
    #pragma unroll
    for (int j=0; j<4; j++){
      unsigned partner = (unsigned)__shfl_xor((int)pk[j], 1, 64);
      unsigned word; int kcol;
      if ((fr & 1) == 0){
        word = (pk[j] & 0xFFFFu) | (partner << 16);
        kcol = fr;
      } else {
        word = (partner >> 16) | (pk[j] & 0xFFFF0000u);
        kcol = 15 + fr;
      }
      int q = fq*4 + j;
      *(unsigned*)&Pl[wid][q][kcol] = word;
    }
    __syncthreads();

    bf16x8 pa = *(const bf16x8*)&Pl[wid][fr][fq*8];
    #pragma unroll
    for (int df=0; df<4; df++){
      const int dr = df*16 + fr, co = fq*8;
      bf16x8 vrh = *(const bf16x8*)&Vrh[dr][co];
      bf16x8 vrl = *(const bf16x8*)&Vrl[dr][co];
      bf16x8 vih = *(const bf16x8*)&Vih[dr][co];
      bf16x8 vil = *(const bf16x8*)&Vil[dr][co];
      f32x4 cr = accOr[df], ci = accOi[df];
      cr = __builtin_amdgcn_mfma_f32_16x16x32_bf16(pa, vrh, cr, 0,0,0);
      cr = __builtin_amdgcn_mfma_f32_16x16x32_bf16(pa, vrl, cr, 0,0,0);
      ci = __builtin_amdgcn_mfma_f32_16x16x32_bf16(pa, vih, ci, 0,0,0);
      ci = __builtin_amdgcn_mfma_f32_16x16x32_bf16(pa, vil, ci, 0,0,0);
      accOr[df] = cr; accOi[df] = ci;
    }
  }

  #pragma unroll
  for (int j=0; j<4; j++){
    float invl = 1.0f / l[j];
    size_t r = (size_t)b*NN + qt*64 + wid*16 + fq*4 + j;
    #pragma unroll
    for (int df=0; df<4; df++){
      int col = h*DD + df*16 + fr;
      aor[r*EE + col] = accOr[df][j] * invl;
      aoi[r*EE + col] = accOi[df][j] * invl;
    }
  }
}

extern "C" void kernel_launch(void* const* d_in, const int* in_sizes, int n_in,
                              void* d_out, int out_size, void* d_ws, size_t ws_size,
                              hipStream_t stream) {
  const float* x       = (const float*)d_in[0];
  const float* g1      = (const float*)d_in[1];
  const float* b1      = (const float*)d_in[2];
  const float* g2      = (const float*)d_in[3];
  const float* b2      = (const float*)d_in[4];
  const float* qkv_wr  = (const float*)d_in[5];
  const float* qkv_wi  = (const float*)d_in[6];
  const float* qkv_br  = (const float*)d_in[7];
  const float* qkv_bi  = (const float*)d_in[8];
  const float* proj_wr = (const float*)d_in[9];
  const float* proj_wi = (const float*)d_in[10];
  const float* proj_br = (const float*)d_in[11];
  const float* proj_bi = (const float*)d_in[12];
  const float* m1_wr   = (const float*)d_in[13];
  const float* m1_wi   = (const float*)d_in[14];
  const float* m1_br   = (const float*)d_in[15];
  const float* m1_bi   = (const float*)d_in[16];
  const float* m2_wr   = (const float*)d_in[17];
  const float* m2_wi   = (const float*)d_in[18];
  const float* m2_br   = (const float*)d_in[19];
  const float* m2_bi   = (const float*)d_in[20];

  float* ws = (float*)d_ws;
  const size_t RE = (size_t)RR * EE;
  // region A (2*RE f32): xn1, then attention output
  float* xn_r  = ws;            float* xn_i  = ws + RE;
  float* ao_r  = ws;            float* ao_i  = ws + RE;
  // region B: QKV split bf16 arrays; later reused as xn2 + mlp hidden
  bf16_t* qsplit = (bf16_t*)(ws + 2*RE);
  float* xn2_r = ws + 2*RE;     float* xn2_i = ws + 3*RE;
  float* h_r   = ws + 4*RE;     float* h_i   = ws + 6*RE;
  // region C (2*RE): post-attention residual state x1
  float* x1_r  = ws + 8*RE;     float* x1_i  = ws + 9*RE;

  // 1. LN1 (interleaved in)
  cln_kernel<<<RR, 256, 0, stream>>>(x, nullptr, nullptr, g1, b1, xn_r, xn_i, 0);
  // 2. QKV clinear -> split bf16 arrays for attention
  cgemm_mfma<0,0,2><<<dim3(36,32), 256, 0, stream>>>(
      xn_r, xn_i, qkv_wr, qkv_wi, qkv_br, qkv_bi,
      nullptr, nullptr, nullptr, nullptr, qsplit, EE, 3*EE);
  // 3. attention -> ao [R][E] planar
  cattn_mfma<<<dim3(16,48), 256, 0, stream>>>(qsplit, ao_r, ao_i);
  // 4. proj clinear + residual(original x, interleaved) -> x1 planar
  cgemm_mfma<0,2,0><<<dim3(12,32), 256, 0, stream>>>(
      ao_r, ao_i, proj_wr, proj_wi, proj_br, proj_bi,
      x, nullptr, x1_r, x1_i, nullptr, EE, EE);
  // 5. LN2 (planar in)
  cln_kernel<<<RR, 256, 0, stream>>>(nullptr, x1_r, x1_i, g2, b2, xn2_r, xn2_i, 1);
  // 6. MLP1 + exact gelu -> h [R][1536] planar
  cgemm_mfma<1,0,0><<<dim3(24,32), 256, 0, stream>>>(
      xn2_r, xn2_i, m1_wr, m1_wi, m1_br, m1_bi,
      nullptr, nullptr, h_r, h_i, nullptr, EE, MLPH);
  // 7. MLP2 + residual(x1 planar) -> d_out interleaved
  cgemm_mfma<0,1,1><<<dim3(12,32), 256, 0, stream>>>(
      h_r, h_i, m2_wr, m2_wi, m2_br, m2_bi,
      x1_r, x1_i, (float*)d_out, nullptr, nullptr, MLPH, EE);
}